// Round 2
// baseline (304.642 us; speedup 1.0000x reference)
//
#include <hip/hip_runtime.h>
#include <hip/hip_bf16.h>
#include <stdint.h>

// ---------------------------------------------------------------------------
// Net_71373766525077: SNN leaky layer.
//   cur = x @ W^T   (1024x4096 @ 4096x4096, fp32 in, tol ~7.9 on mem -> bf16 MFMA)
//   scan over t: reset=(mem>1); mem=0.9*mem+cur[t]-reset; spk=(mem>1)
//   out = concat(spk_rec, mem_rec)  fp32
//
// R1 -> R2: gemm was 1 block/CU (256 blocks, Occupancy 10.7%) -> split-K S-way
// (S = 4/2/1 by ws_size) for S blocks/CU; scan fuses the S-partial reduction
// and doubles in-flight loads.
// ---------------------------------------------------------------------------

typedef __attribute__((ext_vector_type(8))) short bf16x8;
typedef __attribute__((ext_vector_type(4))) float floatx4;

#define T_STEPS 1024
#define N_IN    4096
#define N_OUT   4096

#define BM 128
#define BN 128
#define BKK 64   // K-chunk per LDS stage (bf16 elements)

__device__ __forceinline__ unsigned short f2bf_rne(float f) {
    unsigned int u = __builtin_bit_cast(unsigned int, f);
    unsigned int r = 0x7FFFu + ((u >> 16) & 1u);
    return (unsigned short)((u + r) >> 16);
}

__global__ __launch_bounds__(256) void cvt_kernel(const float4* __restrict__ in,
                                                  ushort4* __restrict__ out, int n4) {
    int i = blockIdx.x * blockDim.x + threadIdx.x;
    if (i < n4) {
        float4 v = in[i];
        ushort4 o;
        o.x = f2bf_rne(v.x);
        o.y = f2bf_rne(v.y);
        o.z = f2bf_rne(v.z);
        o.w = f2bf_rne(v.w);
        out[i] = o;
    }
}

__device__ __forceinline__ void gload16(const void* g, void* l) {
    __builtin_amdgcn_global_load_lds((const __attribute__((address_space(1))) void*)g,
                                     (__attribute__((address_space(3))) void*)l,
                                     16, 0, 0);
}

// Partial C[z][M][N] = A[M][kBeg:kEnd] * B[N][kBeg:kEnd]^T  (bf16 in, fp32 out)
// 128x128 tile / block, 4 waves (2x2), each wave 64x64 via 4x4 16x16x32 MFMA.
__global__ __launch_bounds__(256) void gemm_bt(const short* __restrict__ A,
                                               const short* __restrict__ B,
                                               float* __restrict__ C,
                                               int kLen) {
    __shared__ short sA[BM * BKK];  // 16 KB
    __shared__ short sB[BN * BKK];  // 16 KB

    const int tid  = threadIdx.x;
    const int lane = tid & 63;
    const int wv   = tid >> 6;
    const int wm   = (wv & 1) * 64;
    const int wn   = (wv >> 1) * 64;
    const long bm  = (long)blockIdx.y * BM;
    const long bn  = (long)blockIdx.x * BN;
    const int kBeg = blockIdx.z * kLen;
    const int kEnd = kBeg + kLen;
    float* __restrict__ Cz = C + (size_t)blockIdx.z * T_STEPS * N_OUT;

    floatx4 acc[4][4] = {};

    const int srow = tid >> 3;       // 0..31
    const int scol = (tid & 7) * 8;  // bf16 offset within 64-wide row
    const short* gA[4];
    const short* gB[4];
    short* lA[4];
    short* lB[4];
#pragma unroll
    for (int p = 0; p < 4; ++p) {
        gA[p] = A + (bm + p * 32 + srow) * (long)N_IN + scol;
        gB[p] = B + (bn + p * 32 + srow) * (long)N_IN + scol;
        lA[p] = sA + p * 2048 + tid * 8;
        lB[p] = sB + p * 2048 + tid * 8;
    }

    const int fm  = lane & 15;
    const int fko = (lane >> 4) * 8;

    for (int k0 = kBeg; k0 < kEnd; k0 += BKK) {
#pragma unroll
        for (int p = 0; p < 4; ++p) gload16(gA[p] + k0, lA[p]);
#pragma unroll
        for (int p = 0; p < 4; ++p) gload16(gB[p] + k0, lB[p]);
        __syncthreads();

#pragma unroll
        for (int ks = 0; ks < 2; ++ks) {
            bf16x8 af[4], bfr[4];
#pragma unroll
            for (int i = 0; i < 4; ++i)
                af[i] = *(const bf16x8*)(sA + (wm + i * 16 + fm) * 64 + ks * 32 + fko);
#pragma unroll
            for (int j = 0; j < 4; ++j)
                bfr[j] = *(const bf16x8*)(sB + (wn + j * 16 + fm) * 64 + ks * 32 + fko);
#pragma unroll
            for (int i = 0; i < 4; ++i)
#pragma unroll
                for (int j = 0; j < 4; ++j)
                    acc[i][j] = __builtin_amdgcn_mfma_f32_16x16x32_bf16(
                        af[i], bfr[j], acc[i][j], 0, 0, 0);
        }
        __syncthreads();
    }

    // C/D layout: col=lane&15, row=(lane>>4)*4+reg  [m89/m91]
    const int cn = lane & 15;
    const int cm = (lane >> 4) * 4;
#pragma unroll
    for (int i = 0; i < 4; ++i)
#pragma unroll
        for (int j = 0; j < 4; ++j)
#pragma unroll
            for (int r = 0; r < 4; ++r)
                Cz[(bm + wm + i * 16 + cm + r) * (long)N_OUT + (bn + wn + j * 16 + cn)] =
                    acc[i][j][r];
}

// One thread per neuron; sums S split-K partials on the fly.
// Double-buffered register prefetch: S*U outstanding loads/wave.
template <int S, int U>
__global__ __launch_bounds__(64) void scan_kernel(const float* __restrict__ cur,
                                                  float* __restrict__ out) {
    const int o = blockIdx.x * 64 + threadIdx.x;
    float* __restrict__ spk  = out;
    float* __restrict__ memo = out + (size_t)T_STEPS * N_OUT;
    const float* __restrict__ p = cur + o;

    float mem = 0.0f;
    float b0[S][U], b1[S][U];

#pragma unroll
    for (int s = 0; s < S; ++s)
#pragma unroll
        for (int j = 0; j < U; ++j)
            b0[s][j] = p[(size_t)s * T_STEPS * N_OUT + (size_t)j * N_OUT];

    for (int t0 = 0; t0 < T_STEPS; t0 += 2 * U) {
#pragma unroll
        for (int s = 0; s < S; ++s)
#pragma unroll
            for (int j = 0; j < U; ++j)
                b1[s][j] = p[(size_t)s * T_STEPS * N_OUT + (size_t)(t0 + U + j) * N_OUT];
#pragma unroll
        for (int j = 0; j < U; ++j) {
            float c = b0[0][j];
#pragma unroll
            for (int s = 1; s < S; ++s) c += b0[s][j];
            float rst = mem > 1.0f ? 1.0f : 0.0f;
            mem = 0.9f * mem + c - rst;
            size_t idx = (size_t)(t0 + j) * N_OUT + o;
            spk[idx]  = mem > 1.0f ? 1.0f : 0.0f;
            memo[idx] = mem;
        }
        const int tn = (t0 + 2 * U < T_STEPS) ? (t0 + 2 * U) : 0;  // dummy tail prefetch
#pragma unroll
        for (int s = 0; s < S; ++s)
#pragma unroll
            for (int j = 0; j < U; ++j)
                b0[s][j] = p[(size_t)s * T_STEPS * N_OUT + (size_t)(tn + j) * N_OUT];
#pragma unroll
        for (int j = 0; j < U; ++j) {
            float c = b1[0][j];
#pragma unroll
            for (int s = 1; s < S; ++s) c += b1[s][j];
            float rst = mem > 1.0f ? 1.0f : 0.0f;
            mem = 0.9f * mem + c - rst;
            size_t idx = (size_t)(t0 + U + j) * N_OUT + o;
            spk[idx]  = mem > 1.0f ? 1.0f : 0.0f;
            memo[idx] = mem;
        }
    }
}

extern "C" void kernel_launch(void* const* d_in, const int* in_sizes, int n_in,
                              void* d_out, int out_size, void* d_ws, size_t ws_size,
                              hipStream_t stream) {
    const float* x = (const float*)d_in[0];  // [1024][4096] fp32
    const float* W = (const float*)d_in[1];  // [4096][4096] fp32
    float* out = (float*)d_out;              // [2][1024][4096] fp32

    char* ws = (char*)d_ws;
    const size_t xbBytes = (size_t)T_STEPS * N_IN * 2;   // 8 MB
    const size_t WbBytes = (size_t)N_OUT * N_IN * 2;     // 33.6 MB
    const size_t partBytes = (size_t)T_STEPS * N_OUT * 4; // 16.8 MB per partial
    short* xb  = (short*)ws;
    short* Wb  = (short*)(ws + xbBytes);
    float* cur = (float*)(ws + xbBytes + WbBytes);

    // Split-K factor: as many partial buffers as the workspace allows.
    int S = 1;
    if (ws_size >= xbBytes + WbBytes + 4 * partBytes)      S = 4;
    else if (ws_size >= xbBytes + WbBytes + 2 * partBytes) S = 2;

    {
        int n4 = T_STEPS * N_IN / 4;
        cvt_kernel<<<n4 / 256, 256, 0, stream>>>((const float4*)x, (ushort4*)xb, n4);
    }
    {
        int n4 = N_OUT * N_IN / 4;
        cvt_kernel<<<n4 / 256, 256, 0, stream>>>((const float4*)W, (ushort4*)Wb, n4);
    }

    gemm_bt<<<dim3(N_OUT / BN, T_STEPS / BM, S), 256, 0, stream>>>(
        xb, Wb, cur, N_IN / S);

    if (S == 4)      scan_kernel<4, 16><<<N_OUT / 64, 64, 0, stream>>>(cur, out);
    else if (S == 2) scan_kernel<2, 32><<<N_OUT / 64, 64, 0, stream>>>(cur, out);
    else             scan_kernel<1, 32><<<N_OUT / 64, 64, 0, stream>>>(cur, out);
}

// Round 3
// 232.027 us; speedup vs baseline: 1.3130x; 1.3130x over previous
//
#include <hip/hip_runtime.h>
#include <hip/hip_bf16.h>
#include <stdint.h>

// ---------------------------------------------------------------------------
// Net_71373766525077: SNN leaky layer.
//   cur = x @ W^T   (1024x4096 @ 4096x4096 fp32; mem tol 7.92 -> bf16 MFMA)
//   scan t: reset=(mem>1); mem=0.9*mem+cur[t]-reset; spk=(mem>1)
//   out = concat(spk_rec[T][N], mem_rec[T][N]) fp32
//
// R2 -> R3: split-K reverted (regressed). GEMM epilogue now writes cur
// TRANSPOSED [N][T] via LDS so the scan reads per-lane-contiguous float4
// with a deep register prefetch; scan gets __launch_bounds__(64,1) so the
// compiler can keep the prefetch buffers in VGPRs (R2 showed VGPR=76 ->
// loads were sunk, scan ran at 518 GB/s latency-bound).
// ---------------------------------------------------------------------------

typedef __attribute__((ext_vector_type(8))) short bf16x8;
typedef __attribute__((ext_vector_type(4))) float floatx4;

#define T_STEPS 1024
#define N_IN    4096
#define N_OUT   4096

#define BM 128
#define BN 128
#define BKK 64   // K-chunk per LDS stage (bf16 elements)

__device__ __forceinline__ unsigned short f2bf_rne(float f) {
    unsigned int u = __builtin_bit_cast(unsigned int, f);
    unsigned int r = 0x7FFFu + ((u >> 16) & 1u);
    return (unsigned short)((u + r) >> 16);
}

__global__ __launch_bounds__(256) void cvt_kernel(const float4* __restrict__ in,
                                                  ushort4* __restrict__ out, int n4) {
    int i = blockIdx.x * blockDim.x + threadIdx.x;
    if (i < n4) {
        float4 v = in[i];
        ushort4 o;
        o.x = f2bf_rne(v.x);
        o.y = f2bf_rne(v.y);
        o.z = f2bf_rne(v.z);
        o.w = f2bf_rne(v.w);
        out[i] = o;
    }
}

__device__ __forceinline__ void gload16(const void* g, void* l) {
    __builtin_amdgcn_global_load_lds((const __attribute__((address_space(1))) void*)g,
                                     (__attribute__((address_space(3))) void*)l,
                                     16, 0, 0);
}

// Ct[N][T] = (A[M][K] * B[N][K]^T)^T, bf16 in, fp32 out (TRANSPOSED output).
// 128x128 tile / block, 4 waves (2x2), each wave 64x64 via 4x4 16x16x32 MFMA.
// Epilogue: 4-pass LDS transpose (32 n-rows x 128 m, pad stride 132) then
// coalesced float4 stores to Ct.
__global__ __launch_bounds__(256) void gemm_bt(const short* __restrict__ A,
                                               const short* __restrict__ B,
                                               float* __restrict__ Ct) {
    __shared__ short sA[BM * BKK];   // 16 KB
    __shared__ short sB[BN * BKK];   // 16 KB
    __shared__ float sT[32 * 132];   // 16.9 KB transpose staging

    const int tid  = threadIdx.x;
    const int lane = tid & 63;
    const int wv   = tid >> 6;
    const int wm   = (wv & 1) * 64;
    const int wn   = (wv >> 1) * 64;
    const long bm  = (long)blockIdx.y * BM;
    const long bn  = (long)blockIdx.x * BN;

    floatx4 acc[4][4] = {};

    const int srow = tid >> 3;       // 0..31
    const int scol = (tid & 7) * 8;  // bf16 offset within 64-wide row
    const short* gA[4];
    const short* gB[4];
    short* lA[4];
    short* lB[4];
#pragma unroll
    for (int p = 0; p < 4; ++p) {
        gA[p] = A + (bm + p * 32 + srow) * (long)N_IN + scol;
        gB[p] = B + (bn + p * 32 + srow) * (long)N_IN + scol;
        lA[p] = sA + p * 2048 + tid * 8;
        lB[p] = sB + p * 2048 + tid * 8;
    }

    const int fm  = lane & 15;
    const int fko = (lane >> 4) * 8;

    for (int k0 = 0; k0 < N_IN; k0 += BKK) {
#pragma unroll
        for (int p = 0; p < 4; ++p) gload16(gA[p] + k0, lA[p]);
#pragma unroll
        for (int p = 0; p < 4; ++p) gload16(gB[p] + k0, lB[p]);
        __syncthreads();

#pragma unroll
        for (int ks = 0; ks < 2; ++ks) {
            bf16x8 af[4], bfr[4];
#pragma unroll
            for (int i = 0; i < 4; ++i)
                af[i] = *(const bf16x8*)(sA + (wm + i * 16 + fm) * 64 + ks * 32 + fko);
#pragma unroll
            for (int j = 0; j < 4; ++j)
                bfr[j] = *(const bf16x8*)(sB + (wn + j * 16 + fm) * 64 + ks * 32 + fko);
#pragma unroll
            for (int i = 0; i < 4; ++i)
#pragma unroll
                for (int j = 0; j < 4; ++j)
                    acc[i][j] = __builtin_amdgcn_mfma_f32_16x16x32_bf16(
                        af[i], bfr[j], acc[i][j], 0, 0, 0);
        }
        __syncthreads();
    }

    // Epilogue. MFMA C/D layout: col(n)=lane&15, row(m)=(lane>>4)*4+reg [m89/m91].
    const int cn = lane & 15;
    const int cm = (lane >> 4) * 4;
    const int srowT = tid >> 3;          // 0..31 (n-row within pass)
    const int scolT = (tid & 7) * 16;    // m column base

#pragma unroll
    for (int p = 0; p < 4; ++p) {
        const int nlo = p * 32;
        if (wn == (nlo & 64)) {          // this wave's n-range covers the pass
            const int j0 = (nlo & 32) >> 4;  // 0 or 2
#pragma unroll
            for (int jj = 0; jj < 2; ++jj) {
                const int j = j0 + jj;
                const int np = wn + j * 16 + cn - nlo;  // 0..31
#pragma unroll
                for (int i = 0; i < 4; ++i)
#pragma unroll
                    for (int r = 0; r < 4; ++r)
                        sT[np * 132 + wm + i * 16 + cm + r] = acc[i][j][r];
            }
        }
        __syncthreads();
        // store 32 rows x 128 cols as float4, 8 lanes cover one 128-B segment
#pragma unroll
        for (int q = 0; q < 4; ++q) {
            float4 v = *(const float4*)&sT[srowT * 132 + scolT + q * 4];
            *(float4*)&Ct[(bn + nlo + srowT) * (long)T_STEPS + bm + scolT + q * 4] = v;
        }
        __syncthreads();
    }
}

// One thread per neuron, cur in [N][T]: per-lane contiguous float4 reads,
// double-buffered 16-float4 (64-step) prefetch. Writes [T][N] lane-coalesced.
#define SU 16
__global__ __launch_bounds__(64, 1) void scan_kernel(const float* __restrict__ Ct,
                                                     float* __restrict__ out) {
    const int o = blockIdx.x * 64 + threadIdx.x;
    float* __restrict__ spk  = out;
    float* __restrict__ memo = out + (size_t)T_STEPS * N_OUT;
    const float4* __restrict__ p = (const float4*)(Ct + (size_t)o * T_STEPS);

    float mem = 0.0f;
    float4 b0[SU], b1[SU];

#pragma unroll
    for (int j = 0; j < SU; ++j) b0[j] = p[j];

    for (int t0 = 0; t0 < T_STEPS; t0 += 2 * 4 * SU) {   // 128 steps / iter
        const int c = t0 >> 6;                            // chunk of 64 steps
#pragma unroll
        for (int j = 0; j < SU; ++j) b1[j] = p[(c + 1) * SU + j];
#pragma unroll
        for (int j = 0; j < SU; ++j) {
            float cv[4] = {b0[j].x, b0[j].y, b0[j].z, b0[j].w};
#pragma unroll
            for (int e = 0; e < 4; ++e) {
                float rst = mem > 1.0f ? 1.0f : 0.0f;
                mem = 0.9f * mem + cv[e] - rst;
                size_t idx = (size_t)(t0 + 4 * j + e) * N_OUT + o;
                spk[idx]  = mem > 1.0f ? 1.0f : 0.0f;
                memo[idx] = mem;
            }
        }
        const int cn2 = (c + 2 < T_STEPS / 64) ? (c + 2) : 0;  // dummy on last iter
#pragma unroll
        for (int j = 0; j < SU; ++j) b0[j] = p[cn2 * SU + j];
#pragma unroll
        for (int j = 0; j < SU; ++j) {
            float cv[4] = {b1[j].x, b1[j].y, b1[j].z, b1[j].w};
#pragma unroll
            for (int e = 0; e < 4; ++e) {
                float rst = mem > 1.0f ? 1.0f : 0.0f;
                mem = 0.9f * mem + cv[e] - rst;
                size_t idx = (size_t)(t0 + 64 + 4 * j + e) * N_OUT + o;
                spk[idx]  = mem > 1.0f ? 1.0f : 0.0f;
                memo[idx] = mem;
            }
        }
    }
}

extern "C" void kernel_launch(void* const* d_in, const int* in_sizes, int n_in,
                              void* d_out, int out_size, void* d_ws, size_t ws_size,
                              hipStream_t stream) {
    const float* x = (const float*)d_in[0];  // [1024][4096] fp32
    const float* W = (const float*)d_in[1];  // [4096][4096] fp32
    float* out = (float*)d_out;              // [2][1024][4096] fp32

    char* ws = (char*)d_ws;
    const size_t xbBytes = (size_t)T_STEPS * N_IN * 2;    // 8 MB
    const size_t WbBytes = (size_t)N_OUT * N_IN * 2;      // 33.6 MB
    short* xb  = (short*)ws;
    short* Wb  = (short*)(ws + xbBytes);
    float* cur = (float*)(ws + xbBytes + WbBytes);        // [N][T] fp32, 16.8 MB

    {
        int n4 = T_STEPS * N_IN / 4;
        cvt_kernel<<<n4 / 256, 256, 0, stream>>>((const float4*)x, (ushort4*)xb, n4);
    }
    {
        int n4 = N_OUT * N_IN / 4;
        cvt_kernel<<<n4 / 256, 256, 0, stream>>>((const float4*)W, (ushort4*)Wb, n4);
    }

    gemm_bt<<<dim3(N_OUT / BN, T_STEPS / BM), 256, 0, stream>>>(xb, Wb, cur);

    scan_kernel<<<N_OUT / 64, 64, 0, stream>>>(cur, out);
}

// Round 4
// 202.955 us; speedup vs baseline: 1.5010x; 1.1432x over previous
//
#include <hip/hip_runtime.h>
#include <hip/hip_bf16.h>
#include <stdint.h>

// ---------------------------------------------------------------------------
// Net_71373766525077: SNN leaky layer.
//   cur = x @ W^T   (1024x4096 @ 4096x4096 fp32; mem tol 7.92 -> bf16 MFMA)
//   scan t: reset=(mem>1); mem=0.9*mem+cur[t]-reset; spk=(mem>1)
//   out = concat(spk_rec[T][N], mem_rec[T][N]) fp32
//
// R3 -> R4:
//  * Scan was ~127us: 64 waves, latency-serialized (2.6 B/cy/wave). Replaced
//    with 2-pass chunked replay: pass1 (64 waves) computes only 32-step
//    boundary mem states (0.5 MB); pass2 replays 32-step chunks with 2048
//    waves (8/CU), fully memory-bound.
//  * GEMM was 1 block/CU (256 blocks). Retiled 128x128 -> 64x128 = 512
//    blocks = 2/CU; bid swizzle keeps same-B-stripe blocks on one XCD.
// ---------------------------------------------------------------------------

typedef __attribute__((ext_vector_type(8))) short bf16x8;
typedef __attribute__((ext_vector_type(4))) float floatx4;

#define T_STEPS 1024
#define N_IN    4096
#define N_OUT   4096

#define GM 64    // gemm M tile
#define GN 128   // gemm N tile
#define BKK 64   // K-chunk per LDS stage (bf16 elements)

#define CHUNK 32                       // replay chunk length (steps)
#define NCHUNK (T_STEPS / CHUNK)       // 32 chunks

__device__ __forceinline__ unsigned short f2bf_rne(float f) {
    unsigned int u = __builtin_bit_cast(unsigned int, f);
    unsigned int r = 0x7FFFu + ((u >> 16) & 1u);
    return (unsigned short)((u + r) >> 16);
}

__global__ __launch_bounds__(256) void cvt_kernel(const float4* __restrict__ in,
                                                  ushort4* __restrict__ out, int n4) {
    int i = blockIdx.x * blockDim.x + threadIdx.x;
    if (i < n4) {
        float4 v = in[i];
        ushort4 o;
        o.x = f2bf_rne(v.x);
        o.y = f2bf_rne(v.y);
        o.z = f2bf_rne(v.z);
        o.w = f2bf_rne(v.w);
        out[i] = o;
    }
}

__device__ __forceinline__ void gload16(const void* g, void* l) {
    __builtin_amdgcn_global_load_lds((const __attribute__((address_space(1))) void*)g,
                                     (__attribute__((address_space(3))) void*)l,
                                     16, 0, 0);
}

// Ct[N][T] = (A[M][K] * B[N][K]^T)^T, bf16 in, fp32 out (transposed output).
// 64x128 tile / block, 512 blocks (2/CU). 4 waves, each 64m x 32n via 4x2 of
// 16x16x32 MFMA. Epilogue: LDS transpose (32 n x 64 m, pad 68) -> float4.
__global__ __launch_bounds__(256) void gemm_bt(const short* __restrict__ A,
                                               const short* __restrict__ B,
                                               float* __restrict__ Ct) {
    __shared__ short sA[GM * BKK];   // 8 KB
    __shared__ short sB[GN * BKK];   // 16 KB
    __shared__ float sT[32 * 68];    // 8.7 KB

    const int tid  = threadIdx.x;
    const int lane = tid & 63;
    const int wv   = tid >> 6;
    const int wn   = wv * 32;        // wave n-offset in tile

    // swizzle: same n_tile -> same XCD (bid % 8 == n_tile % 8)
    const int n_tile = blockIdx.x & 31;
    const int m_tile = blockIdx.x >> 5;
    const long bm = (long)m_tile * GM;
    const long bn = (long)n_tile * GN;

    floatx4 acc[4][2] = {};

    const int srow = tid >> 3;       // 0..31
    const int scol = (tid & 7) * 8;  // bf16 offset within 64-wide row
    const short* gA[2];
    const short* gB[4];
    short* lA[2];
    short* lB[4];
#pragma unroll
    for (int p = 0; p < 2; ++p) {
        gA[p] = A + (bm + p * 32 + srow) * (long)N_IN + scol;
        lA[p] = sA + p * 2048 + tid * 8;
    }
#pragma unroll
    for (int p = 0; p < 4; ++p) {
        gB[p] = B + (bn + p * 32 + srow) * (long)N_IN + scol;
        lB[p] = sB + p * 2048 + tid * 8;
    }

    const int fm  = lane & 15;
    const int fko = (lane >> 4) * 8;

    for (int k0 = 0; k0 < N_IN; k0 += BKK) {
#pragma unroll
        for (int p = 0; p < 2; ++p) gload16(gA[p] + k0, lA[p]);
#pragma unroll
        for (int p = 0; p < 4; ++p) gload16(gB[p] + k0, lB[p]);
        __syncthreads();

#pragma unroll
        for (int ks = 0; ks < 2; ++ks) {
            bf16x8 af[4], bfr[2];
#pragma unroll
            for (int i = 0; i < 4; ++i)
                af[i] = *(const bf16x8*)(sA + (i * 16 + fm) * 64 + ks * 32 + fko);
#pragma unroll
            for (int j = 0; j < 2; ++j)
                bfr[j] = *(const bf16x8*)(sB + (wn + j * 16 + fm) * 64 + ks * 32 + fko);
#pragma unroll
            for (int i = 0; i < 4; ++i)
#pragma unroll
                for (int j = 0; j < 2; ++j)
                    acc[i][j] = __builtin_amdgcn_mfma_f32_16x16x32_bf16(
                        af[i], bfr[j], acc[i][j], 0, 0, 0);
        }
        __syncthreads();
    }

    // Epilogue. MFMA C/D: col(n)=lane&15, row(m)=(lane>>4)*4+reg [m89/m91].
    const int cn = lane & 15;
    const int cm = (lane >> 4) * 4;
    const int trow = tid >> 3;           // 0..31 (n-row)
    const int tcol = (tid & 7) * 8;      // m column base

#pragma unroll
    for (int p = 0; p < 4; ++p) {        // n-pass: 32 n-rows each
        if (wv == p) {                   // exactly wave p owns n in [p*32,p*32+32)
#pragma unroll
            for (int j = 0; j < 2; ++j)
#pragma unroll
                for (int i = 0; i < 4; ++i)
#pragma unroll
                    for (int r = 0; r < 4; ++r)
                        sT[(j * 16 + cn) * 68 + i * 16 + cm + r] = acc[i][j][r];
        }
        __syncthreads();
#pragma unroll
        for (int q = 0; q < 2; ++q) {
            float4 v = *(const float4*)&sT[trow * 68 + tcol + q * 4];
            *(float4*)&Ct[(bn + p * 32 + trow) * (long)T_STEPS + bm + tcol + q * 4] = v;
        }
        __syncthreads();
    }
}

// Pass 1: full sequential scan per neuron, but writes ONLY the membrane state
// at every CHUNK-step boundary: bnd[c][n] = mem before step c*CHUNK.
// 64 blocks x 64 threads; reads Ct [N][T] per-lane contiguous, 16-float4
// double buffer (1 MB in flight chip-wide).
__global__ __launch_bounds__(64, 1) void boundary_kernel(const float* __restrict__ Ct,
                                                         float* __restrict__ bnd) {
    const int n = blockIdx.x * 64 + threadIdx.x;
    const float4* __restrict__ p4 = (const float4*)(Ct + (size_t)n * T_STEPS);

    float mem = 0.0f;
    float4 b[2][16];

#pragma unroll
    for (int j = 0; j < 16; ++j) b[0][j] = p4[j];

#pragma unroll
    for (int g = 0; g < 16; ++g) {               // 16 groups x 64 steps
        const int cb = g & 1;
        if (g + 1 < 16) {
#pragma unroll
            for (int j = 0; j < 16; ++j) b[cb ^ 1][j] = p4[(g + 1) * 16 + j];
        }
        bnd[(size_t)(2 * g) * N_OUT + n] = mem;  // boundary at step g*64
#pragma unroll
        for (int j = 0; j < 16; ++j) {
            if (j == 8) bnd[(size_t)(2 * g + 1) * N_OUT + n] = mem;  // step g*64+32
            float cv[4] = {b[cb][j].x, b[cb][j].y, b[cb][j].z, b[cb][j].w};
#pragma unroll
            for (int e = 0; e < 4; ++e) {
                float rst = mem > 1.0f ? 1.0f : 0.0f;
                mem = 0.9f * mem + cv[e] - rst;
            }
        }
    }
}

// Pass 2: replay. Thread (n, c) restarts from bnd[c][n] and recomputes steps
// [c*CHUNK, (c+1)*CHUNK), writing spk/mem lane-coalesced. 2048 waves (8/CU).
__global__ __launch_bounds__(256) void replay_kernel(const float* __restrict__ Ct,
                                                     const float* __restrict__ bnd,
                                                     float* __restrict__ out) {
    const int lane = threadIdx.x & 63;
    const int w    = threadIdx.x >> 6;
    const int n    = blockIdx.x * 64 + lane;      // 0..4095
    const int c    = blockIdx.y * 4 + w;          // 0..31
    float* __restrict__ spk  = out;
    float* __restrict__ memo = out + (size_t)T_STEPS * N_OUT;

    float mem = bnd[(size_t)c * N_OUT + n];
    const float4* __restrict__ p4 = (const float4*)(Ct + (size_t)n * T_STEPS + c * CHUNK);

    float4 v[8];
#pragma unroll
    for (int j = 0; j < 8; ++j) v[j] = p4[j];

#pragma unroll
    for (int j = 0; j < 8; ++j) {
        float cv[4] = {v[j].x, v[j].y, v[j].z, v[j].w};
#pragma unroll
        for (int e = 0; e < 4; ++e) {
            float rst = mem > 1.0f ? 1.0f : 0.0f;
            mem = 0.9f * mem + cv[e] - rst;
            size_t idx = (size_t)(c * CHUNK + j * 4 + e) * N_OUT + n;
            spk[idx]  = mem > 1.0f ? 1.0f : 0.0f;
            memo[idx] = mem;
        }
    }
}

extern "C" void kernel_launch(void* const* d_in, const int* in_sizes, int n_in,
                              void* d_out, int out_size, void* d_ws, size_t ws_size,
                              hipStream_t stream) {
    const float* x = (const float*)d_in[0];  // [1024][4096] fp32
    const float* W = (const float*)d_in[1];  // [4096][4096] fp32
    float* out = (float*)d_out;              // [2][1024][4096] fp32

    char* ws = (char*)d_ws;
    const size_t xbBytes  = (size_t)T_STEPS * N_IN * 2;   // 8 MB
    const size_t WbBytes  = (size_t)N_OUT * N_IN * 2;     // 33.6 MB
    const size_t CtBytes  = (size_t)N_OUT * T_STEPS * 4;  // 16.8 MB
    short* xb  = (short*)ws;
    short* Wb  = (short*)(ws + xbBytes);
    float* cur = (float*)(ws + xbBytes + WbBytes);        // Ct [N][T]
    float* bnd = (float*)(ws + xbBytes + WbBytes + CtBytes); // [32][4096] 0.5 MB

    {
        int n4 = T_STEPS * N_IN / 4;
        cvt_kernel<<<n4 / 256, 256, 0, stream>>>((const float4*)x, (ushort4*)xb, n4);
    }
    {
        int n4 = N_OUT * N_IN / 4;
        cvt_kernel<<<n4 / 256, 256, 0, stream>>>((const float4*)W, (ushort4*)Wb, n4);
    }

    gemm_bt<<<(N_OUT / GN) * (T_STEPS / GM), 256, 0, stream>>>(xb, Wb, cur);

    boundary_kernel<<<N_OUT / 64, 64, 0, stream>>>(cur, bnd);

    replay_kernel<<<dim3(N_OUT / 64, NCHUNK / 4), 256, 0, stream>>>(cur, bnd, out);
}